// Round 5
// baseline (280.997 us; speedup 1.0000x reference)
//
#include <hip/hip_runtime.h>

// Segmented CRF forward (OneCrfCCKSDecoder), exp-domain + MFMA, R12.1
// (R12 with cvt_pkrtz return-type fix: builtin returns __fp16 vector, not
// _Float16 vector -- capture with auto, assign element-wise).
// T=128, B=512, E=128, EVENTLEN=8, NEG=-10000.
//
// R11 post-mortem: register layout-chaining works (LDS=0, validated), but
// 135us: the lone wave's per-step issue is dominated by 32 v_exp_f32
// (transcendental 1/4 rate) + ~96 f32 VALU recomputing exp(feat)*C every
// step -- work with NO dependence on the recurrence.
//
// R12: hoist exp(feat) into a parallel pre-pass (all 256 CUs, ~10us,
// memory-bound) writing f16(exp(feat)*C_SCALE) into workspace, permuted so
// each serial lane's 32 values/step are contiguous 64B. Serial update becomes
// 16 cvt_pkrtz + 16 v_pk_mul_f16 + 64 MFMA + 32 add: ~half the issue count,
// zero transcendentals in the recurrence.
// Renorm: acc scaled permanently by 1/cmax at boundaries (M += log cmax);
// every update M += LOG_C. Same sums as R11, different association.
//
// MFMA layout chaining (validated R11): v_mfma_f32_16x16x16f16 has
// B[k=4q+r][n=bloc] == D[m=4q+r][n=bloc]; j on M, batch on N, so acc IS
// next step's B operand after elementwise scale+cvt. Zero LDS, zero
// barriers, wave-private. Grid = 32 blocks x 64 threads.

typedef _Float16 f16x4 __attribute__((ext_vector_type(4)));
typedef _Float16 f16x8 __attribute__((ext_vector_type(8)));
typedef float    f32x4 __attribute__((ext_vector_type(4)));

#define NEG_VAL   (-10000.0f)
#define C_SCALE   0.0024787521766663585f   // e^-6
#define LOG_C     6.0f

// ---- pre-pass: ef[t][b][32q+4kp+r] = f16(exp(feats[t][b][16kp+4q+r])*C) ----
__global__ __launch_bounds__(256)
void prep_exp(const float* __restrict__ feats, _Float16* __restrict__ ef)
{
    int id = blockIdx.x * 256 + threadIdx.x;           // 524288 threads
    #pragma unroll
    for (int it = 0; it < 4; ++it, id += 524288) {     // 4x grid-stride = 2.1M
        const int kp = id & 7;
        const int q  = (id >> 3) & 3;
        const int tb = id >> 5;                        // t*512 + b, < 65536
        f32x4 x = *(const f32x4*)(feats + (size_t)tb * 128 + 16 * kp + 4 * q);
        auto lo = __builtin_amdgcn_cvt_pkrtz(__expf(x[0]) * C_SCALE,
                                             __expf(x[1]) * C_SCALE);
        auto hi = __builtin_amdgcn_cvt_pkrtz(__expf(x[2]) * C_SCALE,
                                             __expf(x[3]) * C_SCALE);
        f16x4 o;
        o[0] = (_Float16)lo[0]; o[1] = (_Float16)lo[1];
        o[2] = (_Float16)hi[0]; o[3] = (_Float16)hi[1];
        *(f16x4*)(ef + (size_t)tb * 128 + 32 * q + 4 * kp) = o;
    }
}

__device__ inline f16x4 lo4(f16x8 v) { return __builtin_shufflevector(v, v, 0, 1, 2, 3); }
__device__ inline f16x4 hi4(f16x8 v) { return __builtin_shufflevector(v, v, 4, 5, 6, 7); }

__device__ inline f16x4 cvt4(f32x4 a) {
    auto lo = __builtin_amdgcn_cvt_pkrtz(a[0], a[1]);
    auto hi = __builtin_amdgcn_cvt_pkrtz(a[2], a[3]);
    f16x4 o;
    o[0] = (_Float16)lo[0]; o[1] = (_Float16)lo[1];
    o[2] = (_Float16)hi[0]; o[3] = (_Float16)hi[1];
    return o;
}

__global__ __launch_bounds__(64, 1)
void crf_fwd(const _Float16* __restrict__ ef,   // [128][512][128] f16 (permuted)
             const float* __restrict__ trans,   // [128][128] f32
             float* __restrict__ out)
{
    const int lane = threadIdx.x & 63;
    const int bloc = lane & 15;        // batch-in-tile (n role everywhere)
    const int q    = lane >> 4;        // quad 0..3
    const int b    = blockIdx.x * 16 + bloc;   // global batch

    // ---- A fragments: Afrag[jt][kp][r] = exp(trans[16jt+bloc][16kp+4q+r])
    f16x4 Afrag[8][8];
    #pragma unroll
    for (int jt = 0; jt < 8; ++jt) {
        const float* rowp = trans + (size_t)(16 * jt + bloc) * 128;
        #pragma unroll
        for (int kp = 0; kp < 8; ++kp) {
            f32x4 x = *(const f32x4*)(rowp + 16 * kp + 4 * q);
            f16x4 f;
            f[0] = (_Float16)__expf(x[0]);
            f[1] = (_Float16)__expf(x[1]);
            f[2] = (_Float16)__expf(x[2]);
            f[3] = (_Float16)__expf(x[3]);
            Afrag[jt][kp] = f;
        }
    }
    // te[kp][r] = exp(trans[127][16kp+4q+r])  (acc-layout aligned)
    f32x4 te[8];
    #pragma unroll
    for (int kp = 0; kp < 8; ++kp) {
        f32x4 x = *(const f32x4*)(trans + 127 * 128 + 16 * kp + 4 * q);
        te[kp][0] = __expf(x[0]); te[kp][1] = __expf(x[1]);
        te[kp][2] = __expf(x[2]); te[kp][3] = __expf(x[3]);
    }

    // ---- ef pipeline: lane's 32 values/step are contiguous 64B ----
    const _Float16* efb = ef + (size_t)b * 128 + 32 * q;
    f16x8 cur[4], nx1[4], nx2[4];      // ef16 for t, t+1, t+2
    #pragma unroll
    for (int i = 0; i < 4; ++i) {
        cur[i] = *(const f16x8*)(efb + 1 * 65536 + 8 * i);
        nx1[i] = *(const f16x8*)(efb + 2 * 65536 + 8 * i);
        nx2[i] = *(const f16x8*)(efb + 3 * 65536 + 8 * i);
    }

    f32x4 acc[8];                      // u[b=bloc][j=16i+4q+r], D/B layout
    #pragma unroll
    for (int i = 0; i < 8; ++i) acc[i] = (f32x4){1.f, 1.f, 1.f, 1.f};
    float M     = (b == 0) ? 0.0f : NEG_VAL;  // init_fv zeroes only batch-0 row
    float alpha = 0.0f;

    #pragma unroll 8
    for (int t = 1; t < 128; ++t) {
        const bool upd = (t & 7) != 0;

        if (upd) {
            // ---- B-frags: h[k][b] = f16(acc)*ef16, register-only ----
            M += LOG_C;
            f16x4 Bf[8];
            #pragma unroll
            for (int i = 0; i < 4; ++i) {
                Bf[2 * i]     = cvt4(acc[2 * i])     * lo4(cur[i]);
                Bf[2 * i + 1] = cvt4(acc[2 * i + 1]) * hi4(cur[i]);
            }
            // ---- 64 MFMAs: 8 jt x 8 kp; 2 chains of depth 4 per jt ----
            f32x4 z = {0.f, 0.f, 0.f, 0.f};
            #pragma unroll
            for (int jt = 0; jt < 8; ++jt) {
                f32x4 da = __builtin_amdgcn_mfma_f32_16x16x16f16(Afrag[jt][0], Bf[0], z, 0, 0, 0);
                f32x4 db = __builtin_amdgcn_mfma_f32_16x16x16f16(Afrag[jt][1], Bf[1], z, 0, 0, 0);
                da = __builtin_amdgcn_mfma_f32_16x16x16f16(Afrag[jt][2], Bf[2], da, 0, 0, 0);
                db = __builtin_amdgcn_mfma_f32_16x16x16f16(Afrag[jt][3], Bf[3], db, 0, 0, 0);
                da = __builtin_amdgcn_mfma_f32_16x16x16f16(Afrag[jt][4], Bf[4], da, 0, 0, 0);
                db = __builtin_amdgcn_mfma_f32_16x16x16f16(Afrag[jt][5], Bf[5], db, 0, 0, 0);
                da = __builtin_amdgcn_mfma_f32_16x16x16f16(Afrag[jt][6], Bf[6], da, 0, 0, 0);
                db = __builtin_amdgcn_mfma_f32_16x16x16f16(Afrag[jt][7], Bf[7], db, 0, 0, 0);
                acc[jt] = da + db;     // Bf snapshot taken; safe to overwrite
            }
        } else {
            // ---- boundary: alpha partial (sum) + exact renorm (max);
            //      all 128 j in-wave -> shfl-only, no LDS/barrier ----
            float sp[8];
            float m = acc[0][0];
            #pragma unroll
            for (int kp = 0; kp < 8; ++kp) {
                sp[kp] = acc[kp][0] * te[kp][0] + acc[kp][1] * te[kp][1]
                       + acc[kp][2] * te[kp][2] + acc[kp][3] * te[kp][3];
                m = fmaxf(m, fmaxf(fmaxf(acc[kp][0], acc[kp][1]),
                                   fmaxf(acc[kp][2], acc[kp][3])));
            }
            float s = ((sp[0] + sp[1]) + (sp[2] + sp[3]))
                    + ((sp[4] + sp[5]) + (sp[6] + sp[7]));
            s += __shfl_xor(s, 16, 64);
            s += __shfl_xor(s, 32, 64);
            m = fmaxf(m, __shfl_xor(m, 16, 64));
            m = fmaxf(m, __shfl_xor(m, 32, 64));

            alpha += M + __logf(s);    // per-batch, replicated over q
            // exact renorm: scale acc permanently, book into M
            const float inv = __builtin_amdgcn_rcpf(m);
            #pragma unroll
            for (int kp = 0; kp < 8; ++kp) {
                acc[kp][0] *= inv; acc[kp][1] *= inv;
                acc[kp][2] *= inv; acc[kp][3] *= inv;
            }
            M += __logf(m);
        }

        // ---- rotate ef pipeline (pure register moves + 4 prefetch loads) ----
        if (t + 1 < 128) {
            #pragma unroll
            for (int i = 0; i < 4; ++i) {
                cur[i] = nx1[i];
                nx1[i] = nx2[i];
                if (t + 3 < 128)
                    nx2[i] = *(const f16x8*)(efb + (size_t)(t + 3) * 65536 + 8 * i);
            }
        }
    }

    // ---- terminal accumulation (sum only) ----
    {
        float sp[8];
        #pragma unroll
        for (int kp = 0; kp < 8; ++kp)
            sp[kp] = acc[kp][0] * te[kp][0] + acc[kp][1] * te[kp][1]
                   + acc[kp][2] * te[kp][2] + acc[kp][3] * te[kp][3];
        float s = ((sp[0] + sp[1]) + (sp[2] + sp[3]))
                + ((sp[4] + sp[5]) + (sp[6] + sp[7]));
        s += __shfl_xor(s, 16, 64);
        s += __shfl_xor(s, 32, 64);
        alpha += M + __logf(s);
    }

    // alpha replicated across the 4 q-lanes of each bloc: 64-lane sum = 4x
    // the 16-batch sum for this wave.
    float v = alpha;
    #pragma unroll
    for (int off = 1; off < 64; off <<= 1)
        v += __shfl_xor(v, off, 64);
    if (lane == 0)
        atomicAdd(out, v * (1.0f / (4.0f * 512.0f * 16.0f)));
}

extern "C" void kernel_launch(void* const* d_in, const int* in_sizes, int n_in,
                              void* d_out, int out_size, void* d_ws, size_t ws_size,
                              hipStream_t stream) {
    const float* feats = (const float*)d_in[0];   // [128,512,128] f32
    const float* trans = (const float*)d_in[1];   // [128,128] f32
    float* out = (float*)d_out;                   // scalar f32
    _Float16* ef = (_Float16*)d_ws;               // 16.78 MB workspace

    (void)hipMemsetAsync(out, 0, sizeof(float), stream);
    prep_exp<<<2048, 256, 0, stream>>>(feats, ef);
    crf_fwd<<<32, 64, 0, stream>>>(ef, trans, out);
}

// Round 6
// 106.250 us; speedup vs baseline: 2.6447x; 2.6447x over previous
//
#include <hip/hip_runtime.h>

// Segmented CRF forward (OneCrfCCKSDecoder), exp-domain + MFMA, R13.
// T=128, B=512, E=128, EVENTLEN=8, NEG=-10000.
//
// R12.1 post-mortem: halving per-wave issue work made the 1-wave design
// SLOWER (135->227us; abs VALU halved, abs MFMA const) => 1-wave regime is
// latency/clock floored, not issue-bound. Wave count dominates: R9's 8-wave
// 256-wave config (88us) beats all 32-wave variants.
//
// R13 = R9's proven engine (32 wg x 8 waves, j-split, 1 LDS barrier/step)
// + validated grafts from the R12 branch:
//   1. exp(feat) prepass -> f16 workspace, engine-layout permuted (8B/lane
//      loads; no transcendentals in the serial loop).
//   2. f16 publish: h = cvt4(acc) * ef16 (pk_mul), was f32 mul + cvt.
//   3. renorm applied to acc at boundaries (acc *= rcp(cmax), M += log cmax;
//      updates M += 6) -- R12.1's validated bookkeeping.
//   4. double-buffered H (alternating 4KB halves) closes R9's latent
//      write-after-read race; still one barrier per step.
// MFMA layouts identical to validated R9: A[m=lane&15][k=32kap+8q+i],
// B[k=32kap+8q+i][n=lane&15], D[m=4q+r][n=lane&15]; wave w owns j-tile w.

typedef _Float16 f16x4 __attribute__((ext_vector_type(4)));
typedef _Float16 f16x8 __attribute__((ext_vector_type(8)));
typedef float    f32x4 __attribute__((ext_vector_type(4)));

#define NEG_VAL   (-10000.0f)
#define C_SCALE   0.0024787521766663585f   // e^-6
#define LOG_C     6.0f

// order own LDS writes + join workgroup; does NOT drain vmcnt (feat
// prefetch loads stay in flight across the barrier)
#define LDS_BARRIER() asm volatile("s_waitcnt lgkmcnt(0)\n\ts_barrier" ::: "memory")

// ---- pre-pass: ef16 in engine layout ----
// ef[t*65536 + g*2048 + w*256 + bloc*16 + q*4 + r]
//   = f16( exp(feats[t][16g+bloc][16w+4q+r]) * C_SCALE )
__global__ __launch_bounds__(256)
void prep_exp(const float* __restrict__ feats, _Float16* __restrict__ ef)
{
    int id = blockIdx.x * 256 + threadIdx.x;           // 524288 threads
    #pragma unroll
    for (int it = 0; it < 4; ++it, id += 524288) {     // 4x grid-stride = 2.1M
        const int jj = id & 31;                        // j-quad index, j=4*jj
        const int tb = id >> 5;                        // t*512 + b
        const int b  = tb & 511;
        const int t  = tb >> 9;
        f32x4 x = *(const f32x4*)(feats + (size_t)tb * 128 + 4 * jj);
        auto lo = __builtin_amdgcn_cvt_pkrtz(__expf(x[0]) * C_SCALE,
                                             __expf(x[1]) * C_SCALE);
        auto hi = __builtin_amdgcn_cvt_pkrtz(__expf(x[2]) * C_SCALE,
                                             __expf(x[3]) * C_SCALE);
        f16x4 o;
        o[0] = (_Float16)lo[0]; o[1] = (_Float16)lo[1];
        o[2] = (_Float16)hi[0]; o[3] = (_Float16)hi[1];
        const int off = t * 65536 + (b >> 4) * 2048 + (jj >> 2) * 256
                      + (b & 15) * 16 + (jj & 3) * 4;
        *(f16x4*)(ef + off) = o;
    }
}

__device__ inline f16x4 cvt4(f32x4 a) {
    auto lo = __builtin_amdgcn_cvt_pkrtz(a[0], a[1]);
    auto hi = __builtin_amdgcn_cvt_pkrtz(a[2], a[3]);
    f16x4 o;
    o[0] = (_Float16)lo[0]; o[1] = (_Float16)lo[1];
    o[2] = (_Float16)hi[0]; o[3] = (_Float16)hi[1];
    return o;
}

__global__ __launch_bounds__(512)
void crf_fwd(const _Float16* __restrict__ ef,   // engine-layout f16 exp(feat)*C
             const float* __restrict__ trans,   // [128][128] f32
             float* __restrict__ out)
{
    const int tid  = threadIdx.x;
    const int w    = tid >> 6;         // wave id 0..7 = j-tile tau
    const int lane = tid & 63;
    const int bloc = lane & 15;        // batch-in-tile (n role; m role for A)
    const int q    = lane >> 4;        // quad 0..3
    const int b    = blockIdx.x * 16 + bloc;   // global batch

    // ---- A fragments: exp(T) rows j = 16w + bloc, k = 32kap + 8q + i ----
    f16x8 Afrag[4];
    {
        const float* rowp = trans + (size_t)(16 * w + bloc) * 128;
        #pragma unroll
        for (int kap = 0; kap < 4; ++kap) {
            const f32x4* p = (const f32x4*)(rowp + 32 * kap + 8 * q);
            f32x4 x = p[0], y = p[1];
            f16x8 f;
            f[0] = (_Float16)__expf(x[0]); f[1] = (_Float16)__expf(x[1]);
            f[2] = (_Float16)__expf(x[2]); f[3] = (_Float16)__expf(x[3]);
            f[4] = (_Float16)__expf(y[0]); f[5] = (_Float16)__expf(y[1]);
            f[6] = (_Float16)__expf(y[2]); f[7] = (_Float16)__expf(y[3]);
            Afrag[kap] = f;
        }
    }
    // te in D layout for own tile: te[r] = exp(trans[127][16w + 4q + r])
    f32x4 te;
    {
        f32x4 x = *(const f32x4*)(trans + 127 * 128 + 16 * w + 4 * q);
        te[0] = __expf(x[0]); te[1] = __expf(x[1]);
        te[2] = __expf(x[2]); te[3] = __expf(x[3]);
    }

    // ---- LDS: H double-buffered (2 x 16 batches x 128 k f16, 16B chunks
    //           XOR-swizzled by bloc), Spart/Mpart for boundary exchange ----
    __shared__ __align__(16) char  Hbuf[8192];
    __shared__ float Spart[16 * 8];
    __shared__ float Mpart[16 * 8];

    const int waddr = bloc * 256 + (((2 * w + (q >> 1)) ^ bloc) * 16) + 8 * (q & 1);
    int raddr[4];
    #pragma unroll
    for (int kap = 0; kap < 4; ++kap)
        raddr[kap] = bloc * 256 + (((4 * kap + q) ^ bloc) * 16);

    // ---- feat pipeline: lane loads its 8B f16x4 slice per step ----
    const _Float16* efb = ef + blockIdx.x * 2048 + w * 256 + bloc * 16 + q * 4;
    f16x4 cur, nx1, nx2;               // ef16 for t, t+1, t+2
    cur = *(const f16x4*)(efb + 1 * 65536);
    nx1 = *(const f16x4*)(efb + 2 * 65536);
    nx2 = *(const f16x4*)(efb + 3 * 65536);

    f32x4 acc = {1.f, 1.f, 1.f, 1.f};  // u[b][j], j = 16w + 4q + r
    float M     = (b == 0) ? 0.0f : NEG_VAL;  // init_fv zeroes only batch-0 row
    float alpha = 0.0f;
    int hb = 0;                        // H double-buffer offset

    #pragma unroll 8
    for (int t = 1; t < 128; ++t) {
        const bool upd = (t & 7) != 0;

        if (upd) {
            // ---- publish h = f16(acc) * ef16 (scale inside ef; M += 6) ----
            M += LOG_C;
            f16x4 hh = cvt4(acc) * cur;
            *(f16x4*)(Hbuf + hb + waddr) = hh;
            LDS_BARRIER();

            f16x8 B0 = *(const f16x8*)(Hbuf + hb + raddr[0]);
            f16x8 B1 = *(const f16x8*)(Hbuf + hb + raddr[1]);
            f16x8 B2 = *(const f16x8*)(Hbuf + hb + raddr[2]);
            f16x8 B3 = *(const f16x8*)(Hbuf + hb + raddr[3]);

            // ---- 4 MFMAs, two independent chains ----
            f32x4 z = {0.f, 0.f, 0.f, 0.f};
            f32x4 da = __builtin_amdgcn_mfma_f32_16x16x32_f16(Afrag[0], B0, z, 0, 0, 0);
            f32x4 db = __builtin_amdgcn_mfma_f32_16x16x32_f16(Afrag[1], B1, z, 0, 0, 0);
            da = __builtin_amdgcn_mfma_f32_16x16x32_f16(Afrag[2], B2, da, 0, 0, 0);
            db = __builtin_amdgcn_mfma_f32_16x16x32_f16(Afrag[3], B3, db, 0, 0, 0);
            acc = da + db;
            hb ^= 4096;                // alternate H buffer
        } else {
            // ---- boundary: per-wave partials (sum for alpha, max for renorm)
            float s = acc[0] * te[0] + acc[1] * te[1]
                    + acc[2] * te[2] + acc[3] * te[3];
            float m = fmaxf(fmaxf(acc[0], acc[1]), fmaxf(acc[2], acc[3]));
            s += __shfl_xor(s, 16, 64);
            s += __shfl_xor(s, 32, 64);
            m = fmaxf(m, __shfl_xor(m, 16, 64));
            m = fmaxf(m, __shfl_xor(m, 32, 64));
            if (q == 0) {
                Spart[bloc * 8 + w] = s;
                Mpart[bloc * 8 + w] = m;
            }
            LDS_BARRIER();

            f32x4 sa = *(const f32x4*)&Spart[bloc * 8];
            f32x4 sb = *(const f32x4*)&Spart[bloc * 8 + 4];
            f32x4 ma = *(const f32x4*)&Mpart[bloc * 8];
            f32x4 mb = *(const f32x4*)&Mpart[bloc * 8 + 4];
            float r = ((sa[0] + sa[1]) + (sa[2] + sa[3]))
                    + ((sb[0] + sb[1]) + (sb[2] + sb[3]));
            float cmax = fmaxf(fmaxf(fmaxf(ma[0], ma[1]), fmaxf(ma[2], ma[3])),
                               fmaxf(fmaxf(mb[0], mb[1]), fmaxf(mb[2], mb[3])));

            alpha += M + __logf(r);    // per-batch, replicated over q & waves
            // exact renorm: scale acc permanently, book into M
            const float inv = __builtin_amdgcn_rcpf(cmax);
            acc[0] *= inv; acc[1] *= inv; acc[2] *= inv; acc[3] *= inv;
            M += __logf(cmax);
        }

        // ---- rotate feat pipeline (8B prefetch, 3 steps ahead) ----
        if (t + 1 < 128) {
            cur = nx1;
            nx1 = nx2;
            if (t + 3 < 128) nx2 = *(const f16x4*)(efb + (size_t)(t + 3) * 65536);
        }
    }

    // ---- terminal accumulation (sum exchange only) ----
    {
        float s = acc[0] * te[0] + acc[1] * te[1]
                + acc[2] * te[2] + acc[3] * te[3];
        s += __shfl_xor(s, 16, 64);
        s += __shfl_xor(s, 32, 64);
        if (q == 0) Spart[bloc * 8 + w] = s;
        LDS_BARRIER();
        f32x4 sa = *(const f32x4*)&Spart[bloc * 8];
        f32x4 sb = *(const f32x4*)&Spart[bloc * 8 + 4];
        float r = ((sa[0] + sa[1]) + (sa[2] + sa[3]))
                + ((sb[0] + sb[1]) + (sb[2] + sb[3]));
        alpha += M + __logf(r);
    }

    // alpha is replicated across q and waves; reduce in wave 0.
    if (w == 0) {
        float v = alpha;               // 64 lanes = 4x replication of 16 batches
        #pragma unroll
        for (int off = 1; off < 64; off <<= 1)
            v += __shfl_xor(v, off, 64);
        if (lane == 0)
            atomicAdd(out, v * (1.0f / (4.0f * 512.0f * 16.0f)));
    }
}

extern "C" void kernel_launch(void* const* d_in, const int* in_sizes, int n_in,
                              void* d_out, int out_size, void* d_ws, size_t ws_size,
                              hipStream_t stream) {
    const float* feats = (const float*)d_in[0];   // [128,512,128] f32
    const float* trans = (const float*)d_in[1];   // [128,128] f32
    float* out = (float*)d_out;                   // scalar f32
    _Float16* ef = (_Float16*)d_ws;               // 16.78 MB workspace

    (void)hipMemsetAsync(out, 0, sizeof(float), stream);
    prep_exp<<<2048, 256, 0, stream>>>(feats, ef);
    crf_fwd<<<32, 512, 0, stream>>>(ef, trans, out);
}